// Round 5
// baseline (212.823 us; speedup 1.0000x reference)
//
#include <hip/hip_runtime.h>
#include <hip/hip_cooperative_groups.h>

namespace cg = cooperative_groups;

#define EOS_IDX 2
#define NSPLIT 8

typedef float v4f __attribute__((ext_vector_type(4)));

// Block-wide last-EOS scan of one ids row. All threads must call; returns the
// block-uniform max position where row[j] == EOS_IDX (0 if none).
__device__ __forceinline__ int row_last_eos(const int* __restrict__ row, int S) {
    int m = 0;
    for (int j = threadIdx.x; j < S; j += blockDim.x) {
        if (row[j] == EOS_IDX) m = max(m, j);
    }
    #pragma unroll
    for (int off = 32; off > 0; off >>= 1) m = max(m, __shfl_xor(m, off, 64));
    __shared__ int sm[8];
    const int wid = threadIdx.x >> 6;
    const int nw  = blockDim.x >> 6;
    if ((threadIdx.x & 63) == 0) sm[wid] = m;
    __syncthreads();
    int r = sm[0];
    for (int w = 1; w < nw; ++w) r = max(r, sm[w]);
    return r;
}

// Phase-1 body: stream this block's S-chunk, write pre-scaled partial.
__device__ __forceinline__ void pool_body(const float* __restrict__ feat,
                                          const int* __restrict__ ids,
                                          float* __restrict__ partial,
                                          int S, int D, int jchunk) {
    const int b  = blockIdx.x;
    const int le = row_last_eos(ids + (size_t)b * S, S);
    const float inv = 1.0f / (float)(le - 1);

    const int j0 = blockIdx.y * jchunk;
    const int lo = max(j0, 1);
    const int hi = min(j0 + jchunk, le);

    const int d4n = D >> 2;
    const v4f* base = (const v4f*)(feat + (size_t)b * S * D);
    v4f* pout = (v4f*)(partial + ((size_t)b * NSPLIT + blockIdx.y) * D);

    for (int d4 = threadIdx.x; d4 < d4n; d4 += blockDim.x) {
        v4f s0 = {0.f, 0.f, 0.f, 0.f};
        v4f s1 = s0, s2 = s0, s3 = s0, s4 = s0, s5 = s0, s6 = s0, s7 = s0;
        int j = lo;
        for (; j + 8 <= hi; j += 8) {
            const v4f* p = base + (size_t)j * d4n + d4;
            v4f a0 = __builtin_nontemporal_load(p + 0 * d4n);
            v4f a1 = __builtin_nontemporal_load(p + 1 * d4n);
            v4f a2 = __builtin_nontemporal_load(p + 2 * d4n);
            v4f a3 = __builtin_nontemporal_load(p + 3 * d4n);
            v4f a4 = __builtin_nontemporal_load(p + 4 * d4n);
            v4f a5 = __builtin_nontemporal_load(p + 5 * d4n);
            v4f a6 = __builtin_nontemporal_load(p + 6 * d4n);
            v4f a7 = __builtin_nontemporal_load(p + 7 * d4n);
            s0 += a0; s1 += a1; s2 += a2; s3 += a3;
            s4 += a4; s5 += a5; s6 += a6; s7 += a7;
        }
        for (; j < hi; ++j)
            s0 += __builtin_nontemporal_load(base + (size_t)j * d4n + d4);
        v4f t = ((s0 + s1) + (s2 + s3)) + ((s4 + s5) + (s6 + s7));
        pout[d4] = t * inv;  // always write (ws is poisoned, not zeroed)
    }
}

// Phase-2 body: one block per row sums the NSPLIT pre-scaled partials.
__device__ __forceinline__ void reduce_body(const float* __restrict__ partial,
                                            float* __restrict__ out, int D) {
    const int b   = blockIdx.x;
    const int d4n = D >> 2;
    const v4f* p  = (const v4f*)(partial + (size_t)b * NSPLIT * D);
    v4f* o        = (v4f*)(out + (size_t)b * D);
    for (int d4 = threadIdx.x; d4 < d4n; d4 += blockDim.x) {
        v4f s = {0.f, 0.f, 0.f, 0.f};
        #pragma unroll
        for (int t = 0; t < NSPLIT; ++t) s += p[(size_t)t * d4n + d4];
        o[d4] = s;
    }
}

// Fused cooperative kernel: grid (B, NSPLIT) = 512 blocks x 256 threads
// (2 blocks/CU — trivially co-resident).
__global__ __launch_bounds__(256) void fused_kernel(const float* __restrict__ feat,
                                                    const int* __restrict__ ids,
                                                    float* __restrict__ partial,
                                                    float* __restrict__ out,
                                                    int S, int D, int jchunk) {
    pool_body(feat, ids, partial, S, D, jchunk);
    __threadfence();           // device-scope visibility of partials (cross-XCD)
    cg::this_grid().sync();
    if (blockIdx.y == 0) reduce_body(partial, out, D);
}

// Fallback pair (identical math, two dispatches).
__global__ __launch_bounds__(256) void pool_kernel(const float* __restrict__ feat,
                                                   const int* __restrict__ ids,
                                                   float* __restrict__ partial,
                                                   int S, int D, int jchunk) {
    pool_body(feat, ids, partial, S, D, jchunk);
}

__global__ __launch_bounds__(256) void reduce_kernel(const float* __restrict__ partial,
                                                     float* __restrict__ out, int D) {
    reduce_body(partial, out, D);
}

extern "C" void kernel_launch(void* const* d_in, const int* in_sizes, int n_in,
                              void* d_out, int out_size, void* d_ws, size_t ws_size,
                              hipStream_t stream) {
    const float* feat = (const float*)d_in[0];
    const int*   ids  = (const int*)d_in[1];

    const int BS = in_sizes[1];            // B*S
    int D = in_sizes[0] / BS;              // 1024
    const int B = out_size / D;            // 64
    int S = BS / B;                        // 2048

    float* partial = (float*)d_ws;         // B * NSPLIT * D floats
    float* out = (float*)d_out;

    int jchunk = (S + NSPLIT - 1) / NSPLIT;
    dim3 grid(B, NSPLIT);
    dim3 block(256);

    void* args[] = {(void*)&feat, (void*)&ids, (void*)&partial, (void*)&out,
                    (void*)&S, (void*)&D, (void*)&jchunk};
    hipError_t err = hipLaunchCooperativeKernel((const void*)fused_kernel,
                                                grid, block, args, 0, stream);
    if (err != hipSuccess) {
        // Fallback: proven two-dispatch path (R3, 89.6 us).
        pool_kernel<<<grid, block, 0, stream>>>(feat, ids, partial, S, D, jchunk);
        reduce_kernel<<<B, block, 0, stream>>>(partial, out, D);
    }
}

// Round 6
// 89.397 us; speedup vs baseline: 2.3807x; 2.3807x over previous
//
#include <hip/hip_runtime.h>

#define EOS_IDX 2
#define NSPLIT 16

typedef float v4f __attribute__((ext_vector_type(4)));

// Block-wide last-EOS scan of one ids row. All threads must call; returns the
// block-uniform max position where row[j] == EOS_IDX (0 if none).
__device__ __forceinline__ int row_last_eos(const int* __restrict__ row, int S) {
    int m = 0;
    for (int j = threadIdx.x; j < S; j += blockDim.x) {
        if (row[j] == EOS_IDX) m = max(m, j);
    }
    #pragma unroll
    for (int off = 32; off > 0; off >>= 1) m = max(m, __shfl_xor(m, off, 64));
    __shared__ int sm[8];
    const int wid = threadIdx.x >> 6;
    const int nw  = blockDim.x >> 6;
    if ((threadIdx.x & 63) == 0) sm[wid] = m;
    __syncthreads();
    int r = sm[0];
    for (int w = 1; w < nw; ++w) r = max(r, sm[w]);
    return r;
}

// ---------------------------------------------------------------------------
// Pool: grid (B, NSPLIT), 256 threads. Each block derives last_eos for its row
// (ids row is 8 KB, L2-hot), streams its S-chunk with 8-deep independent
// float4 accumulators (8x16B outstanding loads/thread), and writes its
// PRE-SCALED (x 1/(le-1)) partial sum. Partials are written unconditionally
// (ws is poisoned, not zeroed). 1024 blocks = 4/CU = 16 waves/CU.
// ---------------------------------------------------------------------------
__global__ __launch_bounds__(256) void pool_kernel(const float* __restrict__ feat,
                                                   const int* __restrict__ ids,
                                                   float* __restrict__ partial,
                                                   int S, int D, int jchunk) {
    const int b  = blockIdx.x;
    const int le = row_last_eos(ids + (size_t)b * S, S);
    const float inv = 1.0f / (float)(le - 1);

    const int j0 = blockIdx.y * jchunk;
    const int lo = max(j0, 1);
    const int hi = min(j0 + jchunk, le);

    const int d4n = D >> 2;
    const v4f* base = (const v4f*)(feat + (size_t)b * S * D);
    v4f* pout = (v4f*)(partial + ((size_t)b * NSPLIT + blockIdx.y) * D);

    for (int d4 = threadIdx.x; d4 < d4n; d4 += blockDim.x) {
        v4f s0 = {0.f, 0.f, 0.f, 0.f};
        v4f s1 = s0, s2 = s0, s3 = s0, s4 = s0, s5 = s0, s6 = s0, s7 = s0;
        int j = lo;
        for (; j + 8 <= hi; j += 8) {
            const v4f* p = base + (size_t)j * d4n + d4;
            v4f a0 = __builtin_nontemporal_load(p + 0 * d4n);
            v4f a1 = __builtin_nontemporal_load(p + 1 * d4n);
            v4f a2 = __builtin_nontemporal_load(p + 2 * d4n);
            v4f a3 = __builtin_nontemporal_load(p + 3 * d4n);
            v4f a4 = __builtin_nontemporal_load(p + 4 * d4n);
            v4f a5 = __builtin_nontemporal_load(p + 5 * d4n);
            v4f a6 = __builtin_nontemporal_load(p + 6 * d4n);
            v4f a7 = __builtin_nontemporal_load(p + 7 * d4n);
            s0 += a0; s1 += a1; s2 += a2; s3 += a3;
            s4 += a4; s5 += a5; s6 += a6; s7 += a7;
        }
        for (; j < hi; ++j)
            s0 += __builtin_nontemporal_load(base + (size_t)j * d4n + d4);
        v4f t = ((s0 + s1) + (s2 + s3)) + ((s4 + s5) + (s6 + s7));
        pout[d4] = t * inv;
    }
}

// ---------------------------------------------------------------------------
// Reduce: grid (B, 2), 256 threads; block y sums half the d4 range of the
// NSPLIT pre-scaled partials. 128 blocks -> latency-bound tail halved vs 64.
// ---------------------------------------------------------------------------
__global__ __launch_bounds__(256) void reduce_kernel(const float* __restrict__ partial,
                                                     float* __restrict__ out, int D) {
    const int b    = blockIdx.x;
    const int d4n  = D >> 2;
    const int half = d4n >> 1;
    const int d4lo = blockIdx.y * half;
    const v4f* p   = (const v4f*)(partial + (size_t)b * NSPLIT * D);
    v4f* o         = (v4f*)(out + (size_t)b * D);
    for (int d4 = d4lo + threadIdx.x; d4 < d4lo + half; d4 += blockDim.x) {
        v4f s = {0.f, 0.f, 0.f, 0.f};
        #pragma unroll
        for (int t = 0; t < NSPLIT; ++t) s += p[(size_t)t * d4n + d4];
        o[d4] = s;
    }
}

extern "C" void kernel_launch(void* const* d_in, const int* in_sizes, int n_in,
                              void* d_out, int out_size, void* d_ws, size_t ws_size,
                              hipStream_t stream) {
    const float* feat = (const float*)d_in[0];
    const int*   ids  = (const int*)d_in[1];

    const int BS = in_sizes[1];            // B*S
    const int D  = in_sizes[0] / BS;       // 1024
    const int B  = out_size / D;           // 64
    const int S  = BS / B;                 // 2048

    float* partial = (float*)d_ws;         // B * NSPLIT * D floats

    const int jchunk = (S + NSPLIT - 1) / NSPLIT;
    dim3 pgrid(B, NSPLIT);
    pool_kernel<<<pgrid, 256, 0, stream>>>(feat, ids, partial, S, D, jchunk);

    dim3 rgrid(B, 2);
    reduce_kernel<<<rgrid, 256, 0, stream>>>(partial, (float*)d_out, D);
}